// Round 9
// baseline (1054.154 us; speedup 1.0000x reference)
//
#include <hip/hip_runtime.h>
#include <hip/hip_bf16.h>

typedef __bf16 bf16x8 __attribute__((ext_vector_type(8)));
typedef float f32x4 __attribute__((ext_vector_type(4)));
typedef unsigned short u16;
typedef u16 u16x4 __attribute__((ext_vector_type(4)));

__device__ __forceinline__ u16 bfbits(float f) {
  return __builtin_bit_cast(u16, (__bf16)f);
}

// ---------------- prep: weights -> bf16, bias gather [h][query][key] ----------------
__global__ void wattn_prep(const float* __restrict__ wq, const float* __restrict__ wp,
                           const float* __restrict__ rpb, const int* __restrict__ rpi,
                           u16* __restrict__ wqb, u16* __restrict__ wpb,
                           float* __restrict__ biasb) {
  int i = blockIdx.x * blockDim.x + threadIdx.x;      // 196608 threads
  if (i < 196608) wqb[i] = bfbits(wq[i]);             // w_qkv [768][256]
  if (i < 65536)  wpb[i] = bfbits(wp[i]);             // w_proj [256][256]
  if (i < 32768) {                                    // bias [8][query 64][key 64]
    int h = i >> 12, nm = i & 4095;
    biasb[i] = rpb[rpi[nm] * 8 + h];
  }
}

// ---------------- fused window attention ----------------
// block = 1 window, 512 threads = 8 waves, wave w = head w
// LDS: Xb [64][264] u16 (33792 B) + AoH [32][264] u16 (16896 B) = 50688 B -> 3 blocks/CU.
// Proj is done in two 32-token halves through AoH (tokens are proj's M axis — separable).
// Q,K,V,P in registers via k-slot permutation pi(g,j) = j<4 ? 4g+j : 16+4g+(j-4).
// Bias folded into MFMA C-init. launch_bounds(512,6): cap 85 VGPR for 6 waves/SIMD;
// every phase's live-set audited <= ~82 (split Q/K sweeps, per-ct softmax,
// V sweep with 2-wide xb batching + unroll 1).
__global__ __launch_bounds__(512, 6)
void wattn_main(const float* __restrict__ x,
                const u16* __restrict__ wq, const float* __restrict__ bq,
                const u16* __restrict__ wp, const float* __restrict__ bp,
                const float* __restrict__ bias,
                float* __restrict__ out) {
  extern __shared__ u16 sm[];
  u16* Xb  = sm;                      // 64*264
  u16* AoH = sm + 16896;              // 32*264

  const int b    = blockIdx.x;
  const int tid  = threadIdx.x;
  const int w    = tid >> 6;          // wave = head
  const int lane = tid & 63;
  const int g    = lane >> 4;
  const int li   = lane & 15;
  const int hc   = 32 * w;

  // ---- stage x -> bf16 LDS ----
  {
    const float4* xg = (const float4*)(x + (size_t)b * 16384);
    #pragma unroll
    for (int i = 0; i < 8; ++i) {
      int idx = tid + i * 512;
      float4 v = xg[idx];
      int n = idx >> 6, c = (idx & 63) * 4;
      u16x4 h;
      h[0] = bfbits(v.x); h[1] = bfbits(v.y); h[2] = bfbits(v.z); h[3] = bfbits(v.w);
      *(u16x4*)(Xb + n * 264 + c) = h;
    }
  }
  __syncthreads();

  const int xoff = li * 264 + 8 * g;        // per-lane Xb fragment base (u16 units)
  const float scale = 0.17677669529663687f; // 1/sqrt(32)

  // ======== Q sweep: Q^T = Wq . x^T (bias C-init) -> qf ========
  bf16x8 qf[4];
  {
    f32x4 aq[2][4];
    #pragma unroll
    for (int mt = 0; mt < 2; ++mt) {
      f32x4 bqv = *(const f32x4*)(bq + hc + 16 * mt + 4 * g);
      #pragma unroll
      for (int nt = 0; nt < 4; ++nt) aq[mt][nt] = bqv;
    }
    #pragma unroll 2
    for (int ks = 0; ks < 8; ++ks) {
      bf16x8 xb[4];
      #pragma unroll
      for (int nt = 0; nt < 4; ++nt)
        xb[nt] = *(const bf16x8*)(Xb + xoff + nt * (16 * 264) + 32 * ks);
      #pragma unroll
      for (int mt = 0; mt < 2; ++mt) {
        bf16x8 wf = *(const bf16x8*)(wq + (hc + 16 * mt + li) * 256 + 32 * ks + 8 * g);
        #pragma unroll
        for (int nt = 0; nt < 4; ++nt)
          aq[mt][nt] = __builtin_amdgcn_mfma_f32_16x16x32_bf16(wf, xb[nt], aq[mt][nt], 0, 0, 0);
      }
    }
    #pragma unroll
    for (int j = 0; j < 8; ++j)
      #pragma unroll
      for (int t = 0; t < 4; ++t)
        qf[t][j] = (__bf16)((j < 4 ? aq[0][t][j] : aq[1][t][j - 4]) * scale);
  }
  __builtin_amdgcn_sched_barrier(0);

  // ======== K sweep: K^T = Wk . x^T (bias C-init) -> kf ========
  bf16x8 kf[4];
  {
    f32x4 ak[2][4];
    #pragma unroll
    for (int mt = 0; mt < 2; ++mt) {
      f32x4 bkv = *(const f32x4*)(bq + 256 + hc + 16 * mt + 4 * g);
      #pragma unroll
      for (int nt = 0; nt < 4; ++nt) ak[mt][nt] = bkv;
    }
    #pragma unroll 2
    for (int ks = 0; ks < 8; ++ks) {
      bf16x8 xb[4];
      #pragma unroll
      for (int nt = 0; nt < 4; ++nt)
        xb[nt] = *(const bf16x8*)(Xb + xoff + nt * (16 * 264) + 32 * ks);
      #pragma unroll
      for (int mt = 0; mt < 2; ++mt) {
        bf16x8 wf = *(const bf16x8*)(wq + (256 + hc + 16 * mt + li) * 256 + 32 * ks + 8 * g);
        #pragma unroll
        for (int nt = 0; nt < 4; ++nt)
          ak[mt][nt] = __builtin_amdgcn_mfma_f32_16x16x32_bf16(wf, xb[nt], ak[mt][nt], 0, 0, 0);
      }
    }
    #pragma unroll
    for (int j = 0; j < 8; ++j)
      #pragma unroll
      for (int t = 0; t < 4; ++t)
        kf[t][j] = (__bf16)(j < 4 ? ak[0][t][j] : ak[1][t][j - 4]);
  }
  __builtin_amdgcn_sched_barrier(0);

  // ======== S^T = K.Q^T + bias (C-init) per query-tile; softmax; P frags ========
  bf16x8 pa[4][2];
  {
    const float* bh = bias + w * 4096;      // [query][key]
    #pragma unroll
    for (int ct = 0; ct < 4; ++ct) {
      const float* br = bh + (16 * ct + li) * 64 + 4 * g;
      f32x4 s4[4];
      #pragma unroll
      for (int rt = 0; rt < 4; ++rt)
        s4[rt] = __builtin_amdgcn_mfma_f32_16x16x32_bf16(kf[rt], qf[ct],
                                                         *(const f32x4*)(br + 16 * rt), 0, 0, 0);
      float mx = -1e30f;
      #pragma unroll
      for (int rt = 0; rt < 4; ++rt)
        #pragma unroll
        for (int e = 0; e < 4; ++e) mx = fmaxf(mx, s4[rt][e]);
      mx = fmaxf(mx, __shfl_xor(mx, 16));
      mx = fmaxf(mx, __shfl_xor(mx, 32));
      float sum = 0.f;
      #pragma unroll
      for (int rt = 0; rt < 4; ++rt)
        #pragma unroll
        for (int e = 0; e < 4; ++e) {
          float p = __expf(s4[rt][e] - mx);
          s4[rt][e] = p;
          sum += p;
        }
      sum += __shfl_xor(sum, 16);
      sum += __shfl_xor(sum, 32);
      float rs = 1.0f / sum;
      #pragma unroll
      for (int kk = 0; kk < 2; ++kk)
        #pragma unroll
        for (int j = 0; j < 8; ++j)
          pa[ct][kk][j] = (__bf16)((j < 4 ? s4[2 * kk][j] : s4[2 * kk + 1][j - 4]) * rs);
    }
  }
  __builtin_amdgcn_sched_barrier(0);

  // ======== V sweep (unsplit, 2-wide xb batching, unroll 1): V = x . Wv^T ========
  bf16x8 vb[2][2];
  {
    f32x4 av[4][2];
    #pragma unroll
    for (int nt = 0; nt < 2; ++nt) {
      float bb = bq[512 + hc + 16 * nt + li];
      #pragma unroll
      for (int mt = 0; mt < 4; ++mt) av[mt][nt] = f32x4{bb, bb, bb, bb};
    }
    #pragma unroll 1
    for (int ks = 0; ks < 8; ++ks) {
      bf16x8 wf0 = *(const bf16x8*)(wq + (512 + hc + li) * 256 + 32 * ks + 8 * g);
      bf16x8 wf1 = *(const bf16x8*)(wq + (512 + hc + 16 + li) * 256 + 32 * ks + 8 * g);
      bf16x8 x0 = *(const bf16x8*)(Xb + xoff + 0 * (16 * 264) + 32 * ks);
      bf16x8 x1 = *(const bf16x8*)(Xb + xoff + 1 * (16 * 264) + 32 * ks);
      av[0][0] = __builtin_amdgcn_mfma_f32_16x16x32_bf16(x0, wf0, av[0][0], 0, 0, 0);
      av[0][1] = __builtin_amdgcn_mfma_f32_16x16x32_bf16(x0, wf1, av[0][1], 0, 0, 0);
      av[1][0] = __builtin_amdgcn_mfma_f32_16x16x32_bf16(x1, wf0, av[1][0], 0, 0, 0);
      av[1][1] = __builtin_amdgcn_mfma_f32_16x16x32_bf16(x1, wf1, av[1][1], 0, 0, 0);
      bf16x8 x2 = *(const bf16x8*)(Xb + xoff + 2 * (16 * 264) + 32 * ks);
      bf16x8 x3 = *(const bf16x8*)(Xb + xoff + 3 * (16 * 264) + 32 * ks);
      av[2][0] = __builtin_amdgcn_mfma_f32_16x16x32_bf16(x2, wf0, av[2][0], 0, 0, 0);
      av[2][1] = __builtin_amdgcn_mfma_f32_16x16x32_bf16(x2, wf1, av[2][1], 0, 0, 0);
      av[3][0] = __builtin_amdgcn_mfma_f32_16x16x32_bf16(x3, wf0, av[3][0], 0, 0, 0);
      av[3][1] = __builtin_amdgcn_mfma_f32_16x16x32_bf16(x3, wf1, av[3][1], 0, 0, 0);
    }
    // C-frag -> PV B-frag via pi: vb[kk][nt][j] = V[token 32kk+pi(g,j)][d 16nt+li]
    #pragma unroll
    for (int nt = 0; nt < 2; ++nt)
      #pragma unroll
      for (int kk = 0; kk < 2; ++kk)
        #pragma unroll
        for (int j = 0; j < 8; ++j)
          vb[kk][nt][j] = (__bf16)((j < 4 ? av[2 * kk][nt][j] : av[2 * kk + 1][nt][j - 4]));
  }
  __builtin_amdgcn_sched_barrier(0);

  // ======== O = P.V entirely in-register ========
  f32x4 o[4][2];
  #pragma unroll
  for (int mt = 0; mt < 4; ++mt)
    #pragma unroll
    for (int nt = 0; nt < 2; ++nt) o[mt][nt] = f32x4{0, 0, 0, 0};
  #pragma unroll
  for (int kk = 0; kk < 2; ++kk)
    #pragma unroll
    for (int mt = 0; mt < 4; ++mt)
      #pragma unroll
      for (int nt = 0; nt < 2; ++nt)
        o[mt][nt] = __builtin_amdgcn_mfma_f32_16x16x32_bf16(pa[mt][kk], vb[kk][nt], o[mt][nt], 0, 0, 0);

  // ======== proj in two 32-token halves through AoH ========
  float* og = out + (size_t)b * 16384;
  #pragma unroll
  for (int h2 = 0; h2 < 2; ++h2) {
    if (h2) __syncthreads();          // proj0 readers done before overwrite
    // write half: tokens 32*h2 .. 32*h2+31  (o[2h2], o[2h2+1])
    #pragma unroll
    for (int m2 = 0; m2 < 2; ++m2)
      #pragma unroll
      for (int nt = 0; nt < 2; ++nt)
        #pragma unroll
        for (int e = 0; e < 4; ++e)
          AoH[(16 * m2 + 4 * g + e) * 264 + hc + 16 * nt + li] = bfbits(o[2 * h2 + m2][nt][e]);
    __syncthreads();

    // proj half: out rows 32*h2+0..31 = AoH @ Wp^T + bp (C-init)
    f32x4 c2[2][2];
    #pragma unroll
    for (int ct = 0; ct < 2; ++ct) {
      float bb = bp[32 * w + 16 * ct + li];
      #pragma unroll
      for (int rt = 0; rt < 2; ++rt) c2[rt][ct] = f32x4{bb, bb, bb, bb};
    }
    #pragma unroll 2
    for (int ks = 0; ks < 8; ++ks) {
      bf16x8 af[2];
      #pragma unroll
      for (int rt = 0; rt < 2; ++rt)
        af[rt] = *(const bf16x8*)(AoH + xoff + rt * (16 * 264) + 32 * ks);
      bf16x8 wf[2];
      #pragma unroll
      for (int ct = 0; ct < 2; ++ct)
        wf[ct] = *(const bf16x8*)(wp + (32 * w + 16 * ct + li) * 256 + 32 * ks + 8 * g);
      #pragma unroll
      for (int rt = 0; rt < 2; ++rt)
        #pragma unroll
        for (int ct = 0; ct < 2; ++ct)
          c2[rt][ct] = __builtin_amdgcn_mfma_f32_16x16x32_bf16(af[rt], wf[ct], c2[rt][ct], 0, 0, 0);
    }
    #pragma unroll
    for (int ct = 0; ct < 2; ++ct) {
      int col = 32 * w + 16 * ct + li;
      #pragma unroll
      for (int rt = 0; rt < 2; ++rt)
        #pragma unroll
        for (int e = 0; e < 4; ++e)
          og[(32 * h2 + 16 * rt + 4 * g + e) * 256 + col] = c2[rt][ct][e];
    }
  }
}

extern "C" void kernel_launch(void* const* d_in, const int* in_sizes, int n_in,
                              void* d_out, int out_size, void* d_ws, size_t ws_size,
                              hipStream_t stream) {
  const float* x   = (const float*)d_in[0];
  const float* wqv = (const float*)d_in[1];
  const float* bq  = (const float*)d_in[2];
  const float* wpr = (const float*)d_in[3];
  const float* bp  = (const float*)d_in[4];
  const float* rpb = (const float*)d_in[5];
  const int*   rpi = (const int*)d_in[6];
  float* out = (float*)d_out;

  u16*   wqb   = (u16*)d_ws;            // 196608 bf16
  u16*   wpb   = wqb + 196608;          // 65536 bf16
  float* biasb = (float*)(wpb + 65536); // 32768 f32 ([h][query][key])

  wattn_prep<<<384, 512, 0, stream>>>(wqv, wpr, rpb, rpi, wqb, wpb, biasb);

  const size_t smem = (16896 + 8448) * sizeof(u16);  // 50688 B -> 3 blocks/CU
  hipFuncSetAttribute(reinterpret_cast<const void*>(wattn_main),
                      hipFuncAttributeMaxDynamicSharedMemorySize, (int)smem);
  wattn_main<<<8192, 512, smem, stream>>>(x, wqb, bq, wpb, bp, biasb, out);
}

// Round 10
// 968.781 us; speedup vs baseline: 1.0881x; 1.0881x over previous
//
#include <hip/hip_runtime.h>
#include <hip/hip_bf16.h>

typedef __bf16 bf16x8 __attribute__((ext_vector_type(8)));
typedef float f32x4 __attribute__((ext_vector_type(4)));
typedef unsigned short u16;
typedef u16 u16x4 __attribute__((ext_vector_type(4)));

__device__ __forceinline__ u16 bfbits(float f) {
  return __builtin_bit_cast(u16, (__bf16)f);
}

// ---------------- prep: weights -> bf16, bias gather [h][query][key] ----------------
__global__ void wattn_prep(const float* __restrict__ wq, const float* __restrict__ wp,
                           const float* __restrict__ rpb, const int* __restrict__ rpi,
                           u16* __restrict__ wqb, u16* __restrict__ wpb,
                           float* __restrict__ biasb) {
  int i = blockIdx.x * blockDim.x + threadIdx.x;      // 196608 threads
  if (i < 196608) wqb[i] = bfbits(wq[i]);             // w_qkv [768][256]
  if (i < 65536)  wpb[i] = bfbits(wp[i]);             // w_proj [256][256]
  if (i < 32768) {                                    // bias [8][query 64][key 64]
    int h = i >> 12, nm = i & 4095;
    biasb[i] = rpb[rpi[nm] * 8 + h];
  }
}

// ---------------- fused window attention ----------------
// block = 1 window, 512 threads = 8 waves, wave w = head w
// LDS: Xb [64][264] u16 (33792 B) + AoH [32][264] u16 (16896 B) = 50688 B -> 3 blocks/CU.
// True-<=85-VGPR schedule (3rd attempt at (512,6); R4/R9 failed from unroll-2 in-flight
// state + oversized phase peaks). unroll 1 everywhere; every phase's worst-instant
// live set audited <= ~86:
//   K full (ak32+xb16=60) -> V nt-split (av16/half, ~82) -> Q mt-split (aq16/half, ~82)
//   -> per-ct {S, softmax, immediate PV (o transient 8), AoH} (~80)
//   -> proj in 32-token halves after ct1/ct3 (~72).
// pa[4][2] never materializes; o streams to AoH per ct.
__global__ __launch_bounds__(512, 6)
void wattn_main(const float* __restrict__ x,
                const u16* __restrict__ wq, const float* __restrict__ bq,
                const u16* __restrict__ wp, const float* __restrict__ bp,
                const float* __restrict__ bias,
                float* __restrict__ out) {
  extern __shared__ u16 sm[];
  u16* Xb  = sm;                      // 64*264
  u16* AoH = sm + 16896;              // 32*264

  const int b    = blockIdx.x;
  const int tid  = threadIdx.x;
  const int w    = tid >> 6;          // wave = head
  const int lane = tid & 63;
  const int g    = lane >> 4;
  const int li   = lane & 15;
  const int hc   = 32 * w;

  // ---- stage x -> bf16 LDS ----
  {
    const float4* xg = (const float4*)(x + (size_t)b * 16384);
    #pragma unroll
    for (int i = 0; i < 8; ++i) {
      int idx = tid + i * 512;
      float4 v = xg[idx];
      int n = idx >> 6, c = (idx & 63) * 4;
      u16x4 h;
      h[0] = bfbits(v.x); h[1] = bfbits(v.y); h[2] = bfbits(v.z); h[3] = bfbits(v.w);
      *(u16x4*)(Xb + n * 264 + c) = h;
    }
  }
  __syncthreads();

  const int xoff = li * 264 + 8 * g;        // per-lane Xb fragment base (u16 units)
  const float scale = 0.17677669529663687f; // 1/sqrt(32)

  // ======== K sweep (full): K^T = Wk . x^T (bias C-init) -> kf ========
  bf16x8 kf[4];
  {
    f32x4 ak[2][4];
    #pragma unroll
    for (int mt = 0; mt < 2; ++mt) {
      f32x4 bkv = *(const f32x4*)(bq + 256 + hc + 16 * mt + 4 * g);
      #pragma unroll
      for (int nt = 0; nt < 4; ++nt) ak[mt][nt] = bkv;
    }
    #pragma unroll 1
    for (int ks = 0; ks < 8; ++ks) {
      bf16x8 xb[4];
      #pragma unroll
      for (int nt = 0; nt < 4; ++nt)
        xb[nt] = *(const bf16x8*)(Xb + xoff + nt * (16 * 264) + 32 * ks);
      #pragma unroll
      for (int mt = 0; mt < 2; ++mt) {
        bf16x8 wf = *(const bf16x8*)(wq + (256 + hc + 16 * mt + li) * 256 + 32 * ks + 8 * g);
        #pragma unroll
        for (int nt = 0; nt < 4; ++nt)
          ak[mt][nt] = __builtin_amdgcn_mfma_f32_16x16x32_bf16(wf, xb[nt], ak[mt][nt], 0, 0, 0);
      }
    }
    #pragma unroll
    for (int j = 0; j < 8; ++j)
      #pragma unroll
      for (int t = 0; t < 4; ++t)
        kf[t][j] = (__bf16)(j < 4 ? ak[0][t][j] : ak[1][t][j - 4]);
  }
  __builtin_amdgcn_sched_barrier(0);

  // ======== V sweep, nt-split: V = x . Wv^T -> vb (PV B-frags via pi) ========
  bf16x8 vb[2][2];
  #pragma unroll 1
  for (int nt = 0; nt < 2; ++nt) {
    f32x4 av[4];
    {
      float bb = bq[512 + hc + 16 * nt + li];
      #pragma unroll
      for (int mt = 0; mt < 4; ++mt) av[mt] = f32x4{bb, bb, bb, bb};
    }
    #pragma unroll 1
    for (int ks = 0; ks < 8; ++ks) {
      bf16x8 wf = *(const bf16x8*)(wq + (512 + hc + 16 * nt + li) * 256 + 32 * ks + 8 * g);
      #pragma unroll
      for (int mt = 0; mt < 4; ++mt) {
        bf16x8 xb = *(const bf16x8*)(Xb + xoff + mt * (16 * 264) + 32 * ks);
        av[mt] = __builtin_amdgcn_mfma_f32_16x16x32_bf16(xb, wf, av[mt], 0, 0, 0);
      }
    }
    // vb[kk][nt][j] = V[token 32kk+pi(g,j)][d 16nt+li]
    #pragma unroll
    for (int kk = 0; kk < 2; ++kk)
      #pragma unroll
      for (int j = 0; j < 8; ++j)
        vb[kk][nt][j] = (__bf16)(j < 4 ? av[2 * kk][j] : av[2 * kk + 1][j - 4]);
    __builtin_amdgcn_sched_barrier(0);
  }

  // ======== Q sweep, mt-split (d-half): Q^T = Wq . x^T -> qf ========
  bf16x8 qf[4];
  #pragma unroll 1
  for (int mt = 0; mt < 2; ++mt) {
    f32x4 aq[4];
    {
      f32x4 bqv = *(const f32x4*)(bq + hc + 16 * mt + 4 * g);
      #pragma unroll
      for (int nt = 0; nt < 4; ++nt) aq[nt] = bqv;
    }
    #pragma unroll 1
    for (int ks = 0; ks < 8; ++ks) {
      bf16x8 wf = *(const bf16x8*)(wq + (hc + 16 * mt + li) * 256 + 32 * ks + 8 * g);
      #pragma unroll
      for (int nt = 0; nt < 4; ++nt) {
        bf16x8 xb = *(const bf16x8*)(Xb + xoff + nt * (16 * 264) + 32 * ks);
        aq[nt] = __builtin_amdgcn_mfma_f32_16x16x32_bf16(wf, xb, aq[nt], 0, 0, 0);
      }
    }
    #pragma unroll
    for (int t = 0; t < 4; ++t)
      #pragma unroll
      for (int j = 0; j < 4; ++j)
        qf[t][4 * mt + j] = (__bf16)(aq[t][j] * scale);
    __builtin_amdgcn_sched_barrier(0);
  }

  // ======== per-ct: S (bias C-init) -> softmax -> PV -> AoH ; proj halves ========
  float* og = out + (size_t)b * 16384;
  const float* bh = bias + w * 4096;        // [query][key]
  #pragma unroll 1
  for (int ct = 0; ct < 4; ++ct) {
    const float* br = bh + (16 * ct + li) * 64 + 4 * g;
    f32x4 s4[4];
    #pragma unroll
    for (int rt = 0; rt < 4; ++rt)
      s4[rt] = __builtin_amdgcn_mfma_f32_16x16x32_bf16(kf[rt], qf[ct],
                                                       *(const f32x4*)(br + 16 * rt), 0, 0, 0);
    float mx = -1e30f;
    #pragma unroll
    for (int rt = 0; rt < 4; ++rt)
      #pragma unroll
      for (int e = 0; e < 4; ++e) mx = fmaxf(mx, s4[rt][e]);
    mx = fmaxf(mx, __shfl_xor(mx, 16));
    mx = fmaxf(mx, __shfl_xor(mx, 32));
    float sum = 0.f;
    #pragma unroll
    for (int rt = 0; rt < 4; ++rt)
      #pragma unroll
      for (int e = 0; e < 4; ++e) {
        float p = __expf(s4[rt][e] - mx);
        s4[rt][e] = p;
        sum += p;
      }
    sum += __shfl_xor(sum, 16);
    sum += __shfl_xor(sum, 32);
    float rs = 1.0f / sum;
    bf16x8 pa0, pa1;
    #pragma unroll
    for (int j = 0; j < 8; ++j) {
      pa0[j] = (__bf16)((j < 4 ? s4[0][j] : s4[1][j - 4]) * rs);
      pa1[j] = (__bf16)((j < 4 ? s4[2][j] : s4[3][j - 4]) * rs);
    }
    // PV for this query tile: o[nt] = pa0.vb[0][nt] + pa1.vb[1][nt]
    #pragma unroll
    for (int nt = 0; nt < 2; ++nt) {
      f32x4 o = __builtin_amdgcn_mfma_f32_16x16x32_bf16(pa0, vb[0][nt], f32x4{0, 0, 0, 0}, 0, 0, 0);
      o = __builtin_amdgcn_mfma_f32_16x16x32_bf16(pa1, vb[1][nt], o, 0, 0, 0);
      #pragma unroll
      for (int e = 0; e < 4; ++e)
        AoH[(16 * (ct & 1) + 4 * g + e) * 264 + hc + 16 * nt + li] = bfbits(o[e]);
    }
    __builtin_amdgcn_sched_barrier(0);

    if (ct & 1) {
      int h2 = ct >> 1;               // proj half: out tokens 32*h2 .. +31
      __syncthreads();
      f32x4 c2[2][2];
      #pragma unroll
      for (int c = 0; c < 2; ++c) {
        float bb = bp[32 * w + 16 * c + li];
        #pragma unroll
        for (int rt = 0; rt < 2; ++rt) c2[rt][c] = f32x4{bb, bb, bb, bb};
      }
      #pragma unroll 1
      for (int ks = 0; ks < 8; ++ks) {
        bf16x8 af[2];
        #pragma unroll
        for (int rt = 0; rt < 2; ++rt)
          af[rt] = *(const bf16x8*)(AoH + xoff + rt * (16 * 264) + 32 * ks);
        #pragma unroll
        for (int c = 0; c < 2; ++c) {
          bf16x8 wf = *(const bf16x8*)(wp + (32 * w + 16 * c + li) * 256 + 32 * ks + 8 * g);
          #pragma unroll
          for (int rt = 0; rt < 2; ++rt)
            c2[rt][c] = __builtin_amdgcn_mfma_f32_16x16x32_bf16(af[rt], wf, c2[rt][c], 0, 0, 0);
        }
      }
      #pragma unroll
      for (int c = 0; c < 2; ++c) {
        int col = 32 * w + 16 * c + li;
        #pragma unroll
        for (int rt = 0; rt < 2; ++rt)
          #pragma unroll
          for (int e = 0; e < 4; ++e)
            og[(32 * h2 + 16 * rt + 4 * g + e) * 256 + col] = c2[rt][c][e];
      }
      if (h2 == 0) __syncthreads();   // proj0 readers done before ct=2 AoH writes
      __builtin_amdgcn_sched_barrier(0);
    }
  }
}

extern "C" void kernel_launch(void* const* d_in, const int* in_sizes, int n_in,
                              void* d_out, int out_size, void* d_ws, size_t ws_size,
                              hipStream_t stream) {
  const float* x   = (const float*)d_in[0];
  const float* wqv = (const float*)d_in[1];
  const float* bq  = (const float*)d_in[2];
  const float* wpr = (const float*)d_in[3];
  const float* bp  = (const float*)d_in[4];
  const float* rpb = (const float*)d_in[5];
  const int*   rpi = (const int*)d_in[6];
  float* out = (float*)d_out;

  u16*   wqb   = (u16*)d_ws;            // 196608 bf16
  u16*   wpb   = wqb + 196608;          // 65536 bf16
  float* biasb = (float*)(wpb + 65536); // 32768 f32 ([h][query][key])

  wattn_prep<<<384, 512, 0, stream>>>(wqv, wpr, rpb, rpi, wqb, wpb, biasb);

  const size_t smem = (16896 + 8448) * sizeof(u16);  // 50688 B -> 3 blocks/CU
  hipFuncSetAttribute(reinterpret_cast<const void*>(wattn_main),
                      hipFuncAttributeMaxDynamicSharedMemorySize, (int)smem);
  wattn_main<<<8192, 512, smem, stream>>>(x, wqb, bq, wpb, bp, biasb, out);
}

// Round 11
// 937.830 us; speedup vs baseline: 1.1240x; 1.0330x over previous
//
#include <hip/hip_runtime.h>
#include <hip/hip_bf16.h>

typedef __bf16 bf16x8 __attribute__((ext_vector_type(8)));
typedef float f32x4 __attribute__((ext_vector_type(4)));
typedef unsigned short u16;
typedef u16 u16x4 __attribute__((ext_vector_type(4)));
typedef u16 u16x8 __attribute__((ext_vector_type(8)));

__device__ __forceinline__ u16 bfbits(float f) {
  return __builtin_bit_cast(u16, (__bf16)f);
}

// ---------------- prep: weights -> bf16, bias gather [h][query][key] ----------------
__global__ void wattn_prep(const float* __restrict__ wq, const float* __restrict__ wp,
                           const float* __restrict__ rpb, const int* __restrict__ rpi,
                           u16* __restrict__ wqb, u16* __restrict__ wpb,
                           float* __restrict__ biasb) {
  int i = blockIdx.x * blockDim.x + threadIdx.x;      // 196608 threads
  if (i < 196608) wqb[i] = bfbits(wq[i]);             // w_qkv [768][256]
  if (i < 65536)  wpb[i] = bfbits(wp[i]);             // w_proj [256][256]
  if (i < 32768) {                                    // bias [8][query 64][key 64]
    int h = i >> 12, nm = i & 4095;
    biasb[i] = rpb[rpi[nm] * 8 + h];
  }
}

// ================= KERNEL A: attention only -> ao (bf16, [b][64][256]) =================
// 8 waves = 8 heads; LDS = Xb [64][264] only (33792 B). Cap 85 (512,6) -> 3 blocks/CU.
// No proj state in the ct loop: peak live ~80 regs.
__global__ __launch_bounds__(512, 6)
void wattn_attn(const float* __restrict__ x,
                const u16* __restrict__ wq, const float* __restrict__ bq,
                const float* __restrict__ bias,
                u16* __restrict__ ao) {
  extern __shared__ u16 sm[];
  u16* Xb = sm;                       // 64*264

  const int b    = blockIdx.x;
  const int tid  = threadIdx.x;
  const int w    = tid >> 6;
  const int lane = tid & 63;
  const int g    = lane >> 4;
  const int li   = lane & 15;
  const int hc   = 32 * w;

  {
    const float4* xg = (const float4*)(x + (size_t)b * 16384);
    #pragma unroll
    for (int i = 0; i < 8; ++i) {
      int idx = tid + i * 512;
      float4 v = xg[idx];
      int n = idx >> 6, c = (idx & 63) * 4;
      u16x4 h;
      h[0] = bfbits(v.x); h[1] = bfbits(v.y); h[2] = bfbits(v.z); h[3] = bfbits(v.w);
      *(u16x4*)(Xb + n * 264 + c) = h;
    }
  }
  __syncthreads();

  const int xoff = li * 264 + 8 * g;
  const float scale = 0.17677669529663687f;

  // ---- K sweep (full) ----
  bf16x8 kf[4];
  {
    f32x4 ak[2][4];
    #pragma unroll
    for (int mt = 0; mt < 2; ++mt) {
      f32x4 bkv = *(const f32x4*)(bq + 256 + hc + 16 * mt + 4 * g);
      #pragma unroll
      for (int nt = 0; nt < 4; ++nt) ak[mt][nt] = bkv;
    }
    #pragma unroll 1
    for (int ks = 0; ks < 8; ++ks) {
      bf16x8 xb[4];
      #pragma unroll
      for (int nt = 0; nt < 4; ++nt)
        xb[nt] = *(const bf16x8*)(Xb + xoff + nt * (16 * 264) + 32 * ks);
      #pragma unroll
      for (int mt = 0; mt < 2; ++mt) {
        bf16x8 wf = *(const bf16x8*)(wq + (256 + hc + 16 * mt + li) * 256 + 32 * ks + 8 * g);
        #pragma unroll
        for (int nt = 0; nt < 4; ++nt)
          ak[mt][nt] = __builtin_amdgcn_mfma_f32_16x16x32_bf16(wf, xb[nt], ak[mt][nt], 0, 0, 0);
      }
    }
    #pragma unroll
    for (int j = 0; j < 8; ++j)
      #pragma unroll
      for (int t = 0; t < 4; ++t)
        kf[t][j] = (__bf16)(j < 4 ? ak[0][t][j] : ak[1][t][j - 4]);
  }
  __builtin_amdgcn_sched_barrier(0);

  // ---- V sweep (nt-split) ----
  bf16x8 vb[2][2];
  #pragma unroll 1
  for (int nt = 0; nt < 2; ++nt) {
    f32x4 av[4];
    {
      float bb = bq[512 + hc + 16 * nt + li];
      #pragma unroll
      for (int mt = 0; mt < 4; ++mt) av[mt] = f32x4{bb, bb, bb, bb};
    }
    #pragma unroll 1
    for (int ks = 0; ks < 8; ++ks) {
      bf16x8 wf = *(const bf16x8*)(wq + (512 + hc + 16 * nt + li) * 256 + 32 * ks + 8 * g);
      #pragma unroll
      for (int mt = 0; mt < 4; ++mt) {
        bf16x8 xb = *(const bf16x8*)(Xb + xoff + mt * (16 * 264) + 32 * ks);
        av[mt] = __builtin_amdgcn_mfma_f32_16x16x32_bf16(xb, wf, av[mt], 0, 0, 0);
      }
    }
    #pragma unroll
    for (int kk = 0; kk < 2; ++kk)
      #pragma unroll
      for (int j = 0; j < 8; ++j)
        vb[kk][nt][j] = (__bf16)(j < 4 ? av[2 * kk][j] : av[2 * kk + 1][j - 4]);
    __builtin_amdgcn_sched_barrier(0);
  }

  // ---- Q sweep (mt-split) ----
  bf16x8 qf[4];
  #pragma unroll 1
  for (int mt = 0; mt < 2; ++mt) {
    f32x4 aq[4];
    {
      f32x4 bqv = *(const f32x4*)(bq + hc + 16 * mt + 4 * g);
      #pragma unroll
      for (int nt = 0; nt < 4; ++nt) aq[nt] = bqv;
    }
    #pragma unroll 1
    for (int ks = 0; ks < 8; ++ks) {
      bf16x8 wf = *(const bf16x8*)(wq + (hc + 16 * mt + li) * 256 + 32 * ks + 8 * g);
      #pragma unroll
      for (int nt = 0; nt < 4; ++nt) {
        bf16x8 xb = *(const bf16x8*)(Xb + xoff + nt * (16 * 264) + 32 * ks);
        aq[nt] = __builtin_amdgcn_mfma_f32_16x16x32_bf16(wf, xb, aq[nt], 0, 0, 0);
      }
    }
    #pragma unroll
    for (int t = 0; t < 4; ++t)
      #pragma unroll
      for (int j = 0; j < 4; ++j)
        qf[t][4 * mt + j] = (__bf16)(aq[t][j] * scale);
    __builtin_amdgcn_sched_barrier(0);
  }

  // ---- per-ct: S -> softmax -> PV -> ao global ----
  u16* aog = ao + (size_t)b * 16384;
  const float* bh = bias + w * 4096;
  #pragma unroll 1
  for (int ct = 0; ct < 4; ++ct) {
    const float* br = bh + (16 * ct + li) * 64 + 4 * g;
    f32x4 s4[4];
    #pragma unroll
    for (int rt = 0; rt < 4; ++rt)
      s4[rt] = __builtin_amdgcn_mfma_f32_16x16x32_bf16(kf[rt], qf[ct],
                                                       *(const f32x4*)(br + 16 * rt), 0, 0, 0);
    float mx = -1e30f;
    #pragma unroll
    for (int rt = 0; rt < 4; ++rt)
      #pragma unroll
      for (int e = 0; e < 4; ++e) mx = fmaxf(mx, s4[rt][e]);
    mx = fmaxf(mx, __shfl_xor(mx, 16));
    mx = fmaxf(mx, __shfl_xor(mx, 32));
    float sum = 0.f;
    #pragma unroll
    for (int rt = 0; rt < 4; ++rt)
      #pragma unroll
      for (int e = 0; e < 4; ++e) {
        float p = __expf(s4[rt][e] - mx);
        s4[rt][e] = p;
        sum += p;
      }
    sum += __shfl_xor(sum, 16);
    sum += __shfl_xor(sum, 32);
    float rs = 1.0f / sum;
    bf16x8 pa0, pa1;
    #pragma unroll
    for (int j = 0; j < 8; ++j) {
      pa0[j] = (__bf16)((j < 4 ? s4[0][j] : s4[1][j - 4]) * rs);
      pa1[j] = (__bf16)((j < 4 ? s4[2][j] : s4[3][j - 4]) * rs);
    }
    #pragma unroll
    for (int nt = 0; nt < 2; ++nt) {
      f32x4 o = __builtin_amdgcn_mfma_f32_16x16x32_bf16(pa0, vb[0][nt], f32x4{0, 0, 0, 0}, 0, 0, 0);
      o = __builtin_amdgcn_mfma_f32_16x16x32_bf16(pa1, vb[1][nt], o, 0, 0, 0);
      #pragma unroll
      for (int e = 0; e < 4; ++e)
        aog[(16 * ct + 4 * g + e) * 256 + hc + 16 * nt + li] = bfbits(o[e]);
    }
    __builtin_amdgcn_sched_barrier(0);
  }
}

// ================= KERNEL B: proj GEMM out = ao @ Wp^T + bp =================
// 64 tokens/block; ao tile staged to LDS (coalesced); wave w -> cols 32w..32w+31.
__global__ __launch_bounds__(512, 6)
void wattn_proj(const u16* __restrict__ ao, const u16* __restrict__ wp,
                const float* __restrict__ bp, float* __restrict__ out) {
  extern __shared__ u16 sm[];        // [64][264]
  const int b    = blockIdx.x;
  const int tid  = threadIdx.x;
  const int w    = tid >> 6;
  const int lane = tid & 63;
  const int g    = lane >> 4;
  const int li   = lane & 15;

  {
    const u16x8* src = (const u16x8*)(ao + (size_t)b * 16384);
    #pragma unroll
    for (int i = 0; i < 4; ++i) {
      int idx = tid + i * 512;        // 0..2047 chunks of 8 u16
      u16x8 v = src[idx];
      int row = idx >> 5, c = (idx & 31) * 8;
      *(u16x8*)(sm + row * 264 + c) = v;
    }
  }
  __syncthreads();

  const int xoff = li * 264 + 8 * g;
  f32x4 c2[4][2];
  #pragma unroll
  for (int c = 0; c < 2; ++c) {
    float bb = bp[32 * w + 16 * c + li];
    #pragma unroll
    for (int rt = 0; rt < 4; ++rt) c2[rt][c] = f32x4{bb, bb, bb, bb};
  }
  #pragma unroll 1
  for (int ks = 0; ks < 8; ++ks) {
    bf16x8 af[4];
    #pragma unroll
    for (int rt = 0; rt < 4; ++rt)
      af[rt] = *(const bf16x8*)(sm + xoff + rt * (16 * 264) + 32 * ks);
    #pragma unroll
    for (int c = 0; c < 2; ++c) {
      bf16x8 wf = *(const bf16x8*)(wp + (32 * w + 16 * c + li) * 256 + 32 * ks + 8 * g);
      #pragma unroll
      for (int rt = 0; rt < 4; ++rt)
        c2[rt][c] = __builtin_amdgcn_mfma_f32_16x16x32_bf16(af[rt], wf, c2[rt][c], 0, 0, 0);
    }
  }
  {
    float* og = out + (size_t)b * 16384;
    #pragma unroll
    for (int c = 0; c < 2; ++c) {
      int col = 32 * w + 16 * c + li;
      #pragma unroll
      for (int rt = 0; rt < 4; ++rt)
        #pragma unroll
        for (int e = 0; e < 4; ++e)
          og[(16 * rt + 4 * g + e) * 256 + col] = c2[rt][c][e];
    }
  }
}

// ================= FALLBACK: R3 fused kernel (known-good, 704 us) =================
__global__ __launch_bounds__(512, 4)
void wattn_fused(const float* __restrict__ x,
                 const u16* __restrict__ wq, const float* __restrict__ bq,
                 const u16* __restrict__ wp, const float* __restrict__ bp,
                 const float* __restrict__ bias,
                 float* __restrict__ out) {
  extern __shared__ u16 sm[];
  u16* Xb = sm;
  u16* Vt = sm + 16896;

  const int b    = blockIdx.x;
  const int tid  = threadIdx.x;
  const int w    = tid >> 6;
  const int lane = tid & 63;
  const int g    = lane >> 4;
  const int li   = lane & 15;
  const int hc   = 32 * w;

  {
    const float4* xg = (const float4*)(x + (size_t)b * 16384);
    #pragma unroll
    for (int i = 0; i < 8; ++i) {
      int idx = tid + i * 512;
      float4 v = xg[idx];
      int n = idx >> 6, c = (idx & 63) * 4;
      u16x4 h;
      h[0] = bfbits(v.x); h[1] = bfbits(v.y); h[2] = bfbits(v.z); h[3] = bfbits(v.w);
      *(u16x4*)(Xb + n * 264 + c) = h;
    }
  }
  __syncthreads();

  const int xoff = li * 264 + 8 * g;
  const float scale = 0.17677669529663687f;

  f32x4 av[2][4];
  #pragma unroll
  for (int mt = 0; mt < 2; ++mt)
    #pragma unroll
    for (int nt = 0; nt < 4; ++nt) av[mt][nt] = f32x4{0,0,0,0};
  #pragma unroll 2
  for (int ks = 0; ks < 8; ++ks) {
    bf16x8 xb[4];
    #pragma unroll
    for (int nt = 0; nt < 4; ++nt)
      xb[nt] = *(const bf16x8*)(Xb + xoff + nt * (16 * 264) + 32 * ks);
    #pragma unroll
    for (int mt = 0; mt < 2; ++mt) {
      bf16x8 wf = *(const bf16x8*)(wq + (512 + hc + 16 * mt + li) * 256 + 32 * ks + 8 * g);
      #pragma unroll
      for (int nt = 0; nt < 4; ++nt)
        av[mt][nt] = __builtin_amdgcn_mfma_f32_16x16x32_bf16(wf, xb[nt], av[mt][nt], 0, 0, 0);
    }
  }
  {
    u16* VtW = Vt + w * 2304;
    #pragma unroll
    for (int mt = 0; mt < 2; ++mt)
      #pragma unroll
      for (int e = 0; e < 4; ++e) {
        float bb = bq[512 + hc + 16 * mt + 4 * g + e];
        #pragma unroll
        for (int nt = 0; nt < 4; ++nt)
          VtW[(16 * mt + 4 * g + e) * 72 + 16 * nt + li] = bfbits(av[mt][nt][e] + bb);
      }
  }
  __builtin_amdgcn_sched_barrier(0);

  bf16x8 qf[4];
  {
    f32x4 aq[2][4];
    #pragma unroll
    for (int mt = 0; mt < 2; ++mt)
      #pragma unroll
      for (int nt = 0; nt < 4; ++nt) aq[mt][nt] = f32x4{0,0,0,0};
    #pragma unroll 2
    for (int ks = 0; ks < 8; ++ks) {
      bf16x8 xb[4];
      #pragma unroll
      for (int nt = 0; nt < 4; ++nt)
        xb[nt] = *(const bf16x8*)(Xb + xoff + nt * (16 * 264) + 32 * ks);
      #pragma unroll
      for (int mt = 0; mt < 2; ++mt) {
        bf16x8 wf = *(const bf16x8*)(wq + (hc + 16 * mt + li) * 256 + 32 * ks + 8 * g);
        #pragma unroll
        for (int nt = 0; nt < 4; ++nt)
          aq[mt][nt] = __builtin_amdgcn_mfma_f32_16x16x32_bf16(wf, xb[nt], aq[mt][nt], 0, 0, 0);
      }
    }
    #pragma unroll
    for (int j = 0; j < 8; ++j) {
      int d = (j < 4) ? (4 * g + j) : (16 + 4 * g + (j - 4));
      float bb = bq[hc + d];
      #pragma unroll
      for (int t = 0; t < 4; ++t)
        qf[t][j] = (__bf16)(((j < 4 ? aq[0][t][j] : aq[1][t][j - 4]) + bb) * scale);
    }
  }
  __builtin_amdgcn_sched_barrier(0);

  bf16x8 kf[4];
  {
    f32x4 ak[2][4];
    #pragma unroll
    for (int mt = 0; mt < 2; ++mt)
      #pragma unroll
      for (int nt = 0; nt < 4; ++nt) ak[mt][nt] = f32x4{0,0,0,0};
    #pragma unroll 2
    for (int ks = 0; ks < 8; ++ks) {
      bf16x8 xb[4];
      #pragma unroll
      for (int nt = 0; nt < 4; ++nt)
        xb[nt] = *(const bf16x8*)(Xb + xoff + nt * (16 * 264) + 32 * ks);
      #pragma unroll
      for (int mt = 0; mt < 2; ++mt) {
        bf16x8 wf = *(const bf16x8*)(wq + (256 + hc + 16 * mt + li) * 256 + 32 * ks + 8 * g);
        #pragma unroll
        for (int nt = 0; nt < 4; ++nt)
          ak[mt][nt] = __builtin_amdgcn_mfma_f32_16x16x32_bf16(wf, xb[nt], ak[mt][nt], 0, 0, 0);
      }
    }
    #pragma unroll
    for (int j = 0; j < 8; ++j) {
      int d = (j < 4) ? (4 * g + j) : (16 + 4 * g + (j - 4));
      float bb = bq[256 + hc + d];
      #pragma unroll
      for (int t = 0; t < 4; ++t)
        kf[t][j] = (__bf16)((j < 4 ? ak[0][t][j] : ak[1][t][j - 4]) + bb);
    }
  }
  __builtin_amdgcn_sched_barrier(0);

  bf16x8 pa[4][2];
  {
    const float* bh = bias + w * 4096;
    #pragma unroll
    for (int ct = 0; ct < 4; ++ct) {
      f32x4 s4[4];
      #pragma unroll
      for (int rt = 0; rt < 4; ++rt)
        s4[rt] = __builtin_amdgcn_mfma_f32_16x16x32_bf16(kf[rt], qf[ct], f32x4{0,0,0,0}, 0, 0, 0);
      const float* bq_row = bh + (16 * ct + li) * 64 + 4 * g;
      float mx = -1e30f;
      #pragma unroll
      for (int rt = 0; rt < 4; ++rt) {
        f32x4 bv = *(const f32x4*)(bq_row + 16 * rt);
        #pragma unroll
        for (int e = 0; e < 4; ++e) {
          s4[rt][e] += bv[e];
          mx = fmaxf(mx, s4[rt][e]);
        }
      }
      mx = fmaxf(mx, __shfl_xor(mx, 16));
      mx = fmaxf(mx, __shfl_xor(mx, 32));
      float sum = 0.f;
      #pragma unroll
      for (int rt = 0; rt < 4; ++rt)
        #pragma unroll
        for (int e = 0; e < 4; ++e) {
          float p = __expf(s4[rt][e] - mx);
          s4[rt][e] = p;
          sum += p;
        }
      sum += __shfl_xor(sum, 16);
      sum += __shfl_xor(sum, 32);
      float rs = 1.0f / sum;
      #pragma unroll
      for (int kk = 0; kk < 2; ++kk)
        #pragma unroll
        for (int j = 0; j < 8; ++j)
          pa[ct][kk][j] = (__bf16)((j < 4 ? s4[2 * kk][j] : s4[2 * kk + 1][j - 4]) * rs);
      __builtin_amdgcn_sched_barrier(0);
    }
  }

  f32x4 o[4][2];
  #pragma unroll
  for (int mt = 0; mt < 4; ++mt)
    #pragma unroll
    for (int nt = 0; nt < 2; ++nt) o[mt][nt] = f32x4{0,0,0,0};
  {
    const u16* VtW = Vt + w * 2304;
    #pragma unroll
    for (int kk = 0; kk < 2; ++kk) {
      bf16x8 vbf[2];
      #pragma unroll
      for (int nt = 0; nt < 2; ++nt) {
        const u16* row = VtW + (16 * nt + li) * 72;
        u16x4 lo = *(const u16x4*)(row + 32 * kk + 4 * g);
        u16x4 hi = *(const u16x4*)(row + 32 * kk + 16 + 4 * g);
        u16x8 cc;
        #pragma unroll
        for (int j = 0; j < 4; ++j) { cc[j] = lo[j]; cc[4 + j] = hi[j]; }
        vbf[nt] = __builtin_bit_cast(bf16x8, cc);
      }
      #pragma unroll
      for (int mt = 0; mt < 4; ++mt)
        #pragma unroll
        for (int nt = 0; nt < 2; ++nt)
          o[mt][nt] = __builtin_amdgcn_mfma_f32_16x16x32_bf16(pa[mt][kk], vbf[nt], o[mt][nt], 0, 0, 0);
    }
  }

  __syncthreads();
  u16* ao = sm;
  #pragma unroll
  for (int mt = 0; mt < 4; ++mt)
    #pragma unroll
    for (int nt = 0; nt < 2; ++nt)
      #pragma unroll
      for (int e = 0; e < 4; ++e)
        ao[(16 * mt + 4 * g + e) * 264 + hc + 16 * nt + li] = bfbits(o[mt][nt][e]);
  __syncthreads();

  f32x4 c2[4][2];
  #pragma unroll
  for (int rt = 0; rt < 4; ++rt)
    #pragma unroll
    for (int ct = 0; ct < 2; ++ct) c2[rt][ct] = f32x4{0,0,0,0};
  #pragma unroll 2
  for (int ks = 0; ks < 8; ++ks) {
    bf16x8 af[4];
    #pragma unroll
    for (int rt = 0; rt < 4; ++rt)
      af[rt] = *(const bf16x8*)(ao + xoff + rt * (16 * 264) + 32 * ks);
    bf16x8 wf[2];
    #pragma unroll
    for (int ct = 0; ct < 2; ++ct)
      wf[ct] = *(const bf16x8*)(wp + (32 * w + 16 * ct + li) * 256 + 32 * ks + 8 * g);
    #pragma unroll
    for (int rt = 0; rt < 4; ++rt)
      #pragma unroll
      for (int ct = 0; ct < 2; ++ct)
        c2[rt][ct] = __builtin_amdgcn_mfma_f32_16x16x32_bf16(af[rt], wf[ct], c2[rt][ct], 0, 0, 0);
  }
  {
    float* og = out + (size_t)b * 16384;
    #pragma unroll
    for (int ct = 0; ct < 2; ++ct) {
      int col = 32 * w + 16 * ct + li;
      float bpv = bp[col];
      #pragma unroll
      for (int rt = 0; rt < 4; ++rt)
        #pragma unroll
        for (int e = 0; e < 4; ++e)
          og[(16 * rt + 4 * g + e) * 256 + col] = c2[rt][ct][e] + bpv;
    }
  }
}

extern "C" void kernel_launch(void* const* d_in, const int* in_sizes, int n_in,
                              void* d_out, int out_size, void* d_ws, size_t ws_size,
                              hipStream_t stream) {
  const float* x   = (const float*)d_in[0];
  const float* wqv = (const float*)d_in[1];
  const float* bq  = (const float*)d_in[2];
  const float* wpr = (const float*)d_in[3];
  const float* bp  = (const float*)d_in[4];
  const float* rpb = (const float*)d_in[5];
  const int*   rpi = (const int*)d_in[6];
  float* out = (float*)d_out;

  u16*   wqb   = (u16*)d_ws;            // 196608 bf16
  u16*   wpb   = wqb + 196608;          // 65536 bf16
  float* biasb = (float*)(wpb + 65536); // 32768 f32
  u16*   ao    = (u16*)((char*)d_ws + 655360);  // 268435456 B intermediate

  wattn_prep<<<384, 512, 0, stream>>>(wqv, wpr, rpb, rpi, wqb, wpb, biasb);

  const size_t need = 655360u + 268435456u;
  if (ws_size >= need) {
    const size_t smemA = 16896 * sizeof(u16);
    wattn_attn<<<8192, 512, smemA, stream>>>(x, wqb, bq, biasb, ao);
    wattn_proj<<<8192, 512, smemA, stream>>>(ao, wpb, bp, out);
  } else {
    const size_t smemF = (16896 + 18432) * sizeof(u16);
    hipFuncSetAttribute(reinterpret_cast<const void*>(wattn_fused),
                        hipFuncAttributeMaxDynamicSharedMemorySize, (int)smemF);
    wattn_fused<<<8192, 512, smemF, stream>>>(x, wqb, bq, wpb, bp, biasb, out);
  }
}